// Round 5
// baseline (337.507 us; speedup 1.0000x reference)
//
#include <hip/hip_runtime.h>

#define HH 256   // H
#define BB 64    // B
#define KK 32    // K
#define LL 64    // L
#define LGRP 8   // l's per edge-kernel block

typedef __bf16 bf16_t;
typedef __attribute__((ext_vector_type(8))) __bf16 bf16x8;
typedef __attribute__((ext_vector_type(4))) float f32x4;

// ---- load 8 contiguous f32 -> bf16x8 ----
__device__ __forceinline__ bf16x8 ld_a8(const float* __restrict__ p) {
  const f32x4* q = (const f32x4*)p;
  f32x4 a = q[0], b = q[1];
  bf16x8 r;
  r[0] = (__bf16)a[0]; r[1] = (__bf16)a[1]; r[2] = (__bf16)a[2]; r[3] = (__bf16)a[3];
  r[4] = (__bf16)b[0]; r[5] = (__bf16)b[1]; r[6] = (__bf16)b[2]; r[7] = (__bf16)b[3];
  return r;
}
__device__ __forceinline__ bf16x8 ld_a8s(const float* __restrict__ p, float sc) {
  const f32x4* q = (const f32x4*)p;
  f32x4 a = q[0], b = q[1];
  bf16x8 r;
  r[0] = (__bf16)(a[0]*sc); r[1] = (__bf16)(a[1]*sc); r[2] = (__bf16)(a[2]*sc); r[3] = (__bf16)(a[3]*sc);
  r[4] = (__bf16)(b[0]*sc); r[5] = (__bf16)(b[1]*sc); r[6] = (__bf16)(b[2]*sc); r[7] = (__bf16)(b[3]*sc);
  return r;
}
// sum 8 partial slices (stride 524288 f32) -> bf16x8
__device__ __forceinline__ bf16x8 ld_sum8(const float* __restrict__ p) {
  f32x4 s0 = {0.f,0.f,0.f,0.f}, s1 = s0;
#pragma unroll
  for (int lc = 0; lc < 8; ++lc) {
    const f32x4* q = (const f32x4*)(p + (size_t)lc * 524288);
    s0 += q[0]; s1 += q[1];
  }
  bf16x8 r;
  r[0] = (__bf16)s0[0]; r[1] = (__bf16)s0[1]; r[2] = (__bf16)s0[2]; r[3] = (__bf16)s0[3];
  r[4] = (__bf16)s1[0]; r[5] = (__bf16)s1[1]; r[6] = (__bf16)s1[2]; r[7] = (__bf16)s1[3];
  return r;
}

// ---- e-tile staging (512 threads): 16 f32/thread -> regs -> swizzled bf16 LDS ----
__device__ __forceinline__ void ld_tile(const float* __restrict__ E, int tid, f32x4 r[4]) {
  const f32x4* q = (const f32x4*)(E + tid * 16);
  r[0] = q[0]; r[1] = q[1]; r[2] = q[2]; r[3] = q[3];
}
__device__ __forceinline__ void wr_tile(bf16_t* buf, int tid, const f32x4 r[4]) {
  int row = tid >> 4;
  int colb = (tid & 15) * 32;
  bf16x8 v0, v1;
  v0[0] = (__bf16)r[0][0]; v0[1] = (__bf16)r[0][1]; v0[2] = (__bf16)r[0][2]; v0[3] = (__bf16)r[0][3];
  v0[4] = (__bf16)r[1][0]; v0[5] = (__bf16)r[1][1]; v0[6] = (__bf16)r[1][2]; v0[7] = (__bf16)r[1][3];
  v1[0] = (__bf16)r[2][0]; v1[1] = (__bf16)r[2][1]; v1[2] = (__bf16)r[2][2]; v1[3] = (__bf16)r[2][3];
  v1[4] = (__bf16)r[3][0]; v1[5] = (__bf16)r[3][1]; v1[6] = (__bf16)r[3][2]; v1[7] = (__bf16)r[3][3];
  int swz = (row & 7) << 4;
  *(bf16x8*)((char*)buf + row * 512 + (colb ^ swz)) = v0;
  *(bf16x8*)((char*)buf + row * 512 + ((colb + 16) ^ swz)) = v1;
}

// acc[2][4] += A(32x256 f32 global)*B(f32 global, cvt+scale)^T  (4-wave, 64-col wave)
template<int LDB>
__device__ __forceinline__ void mm_f32AB(const float* __restrict__ A,
                                         const float* __restrict__ B,
                                         f32x4 acc[2][4], int lane, float sc) {
  const int c = lane & 15, g = lane >> 4;
#pragma unroll
  for (int ks = 0; ks < 8; ++ks) {
    const int ko = ks * 32 + g * 8;
    bf16x8 a0 = ld_a8(A + (size_t)c * HH + ko);
    bf16x8 a1 = ld_a8(A + (size_t)(16 + c) * HH + ko);
#pragma unroll
    for (int nt = 0; nt < 4; ++nt) {
      bf16x8 bb = ld_a8s(B + (size_t)(nt * 16 + c) * LDB + ko, sc);
      acc[0][nt] = __builtin_amdgcn_mfma_f32_16x16x32_bf16(a0, bb, acc[0][nt], 0, 0, 0);
      acc[1][nt] = __builtin_amdgcn_mfma_f32_16x16x32_bf16(a1, bb, acc[1][nt], 0, 0, 0);
    }
  }
}

// acc[2][4] += (Σ_lc part)(32x256)*B^T  — UE message reduce fused into A-fragments
__device__ __forceinline__ void mm_partA(const float* __restrict__ P,
                                         const float* __restrict__ B,
                                         f32x4 acc[2][4], int lane, float sc) {
  const int c = lane & 15, g = lane >> 4;
#pragma unroll
  for (int ks = 0; ks < 8; ++ks) {
    const int ko = ks * 32 + g * 8;
    bf16x8 a0 = ld_sum8(P + (size_t)c * HH + ko);
    bf16x8 a1 = ld_sum8(P + (size_t)(16 + c) * HH + ko);
#pragma unroll
    for (int nt = 0; nt < 4; ++nt) {
      bf16x8 bb = ld_a8s(B + (size_t)(nt * 16 + c) * HH + ko, sc);
      acc[0][nt] = __builtin_amdgcn_mfma_f32_16x16x32_bf16(a0, bb, acc[0][nt], 0, 0, 0);
      acc[1][nt] = __builtin_amdgcn_mfma_f32_16x16x32_bf16(a1, bb, acc[1][nt], 0, 0, 0);
    }
  }
}

// acc[2][4] += LDS(32x256 bf16 swizzled)*B(f32 global cvt)^T
__device__ __forceinline__ void mm_lds_f32B(const bf16_t* lds,
                                            const float* __restrict__ B,
                                            f32x4 acc[2][4], int lane) {
  const int c = lane & 15, g = lane >> 4;
  const int swz = (c & 7) << 4;
#pragma unroll
  for (int ks = 0; ks < 8; ++ks) {
    const int kb = (ks * 32 + g * 8) * 2;
    bf16x8 a0 = *(const bf16x8*)((const char*)lds + c * 512 + (kb ^ swz));
    bf16x8 a1 = *(const bf16x8*)((const char*)lds + (16 + c) * 512 + (kb ^ swz));
#pragma unroll
    for (int nt = 0; nt < 4; ++nt) {
      bf16x8 bb = ld_a8(B + (size_t)(nt * 16 + c) * HH + ks * 32 + g * 8);
      acc[0][nt] = __builtin_amdgcn_mfma_f32_16x16x32_bf16(a0, bb, acc[0][nt], 0, 0, 0);
      acc[1][nt] = __builtin_amdgcn_mfma_f32_16x16x32_bf16(a1, bb, acc[1][nt], 0, 0, 0);
    }
  }
}

// ============ phase A: p_ue/p_ap in-kernel + layer-1 of both MLPs + reductions ============
__global__ __launch_bounds__(512) void phaseA_kernel(
    const float* __restrict__ e, const float* __restrict__ h_ue,
    const float* __restrict__ h_ap,
    const float* __restrict__ a2u_w1, const float* __restrict__ a2u_b1,
    const float* __restrict__ u2a_w1, const float* __restrict__ u2a_b1,
    float* __restrict__ part, float* __restrict__ R_ap) {
  __shared__ bf16_t ebuf[2][32 * 256];
  __shared__ float pA[8 * 256];
  const int blk = blockIdx.x;              // 512 blocks
  const int b = blk >> 3, lc = blk & 7;
  const int tid = threadIdx.x, w = tid >> 6, lane = tid & 63;
  const int colw = w * 32, c = lane & 15, g = lane >> 4;
  const int l0 = lc * LGRP;

  // issue first e tile loads early
  f32x4 rs[4];
  ld_tile(e + (size_t)((b * LL + l0) * KK) * HH, tid, rs);

  // --- prologue 1: p_ue = h_ue[b]*Wu1_h^T + u2a_b1 (register-direct layout) ---
  float pue[2][2][4];
  {
    f32x4 pacc[2][2];
#pragma unroll
    for (int nt = 0; nt < 2; ++nt) {
      float bv = u2a_b1[colw + nt * 16 + c];
      f32x4 t = {bv, bv, bv, bv};
      pacc[0][nt] = t; pacc[1][nt] = t;
    }
#pragma unroll
    for (int ks = 0; ks < 8; ++ks) {
      const int ko = ks * 32 + g * 8;
      bf16x8 a0 = ld_a8(h_ue + (size_t)(b * KK + c) * HH + ko);
      bf16x8 a1 = ld_a8(h_ue + (size_t)(b * KK + 16 + c) * HH + ko);
#pragma unroll
      for (int nt = 0; nt < 2; ++nt) {
        bf16x8 bb = ld_a8(u2a_w1 + (size_t)(colw + nt * 16 + c) * 512 + ko);
        pacc[0][nt] = __builtin_amdgcn_mfma_f32_16x16x32_bf16(a0, bb, pacc[0][nt], 0, 0, 0);
        pacc[1][nt] = __builtin_amdgcn_mfma_f32_16x16x32_bf16(a1, bb, pacc[1][nt], 0, 0, 0);
      }
    }
#pragma unroll
    for (int m = 0; m < 2; ++m)
#pragma unroll
      for (int nt = 0; nt < 2; ++nt)
#pragma unroll
        for (int rr = 0; rr < 4; ++rr) pue[m][nt][rr] = pacc[m][nt][rr];
  }

  // --- prologue 2: p_ap rows l0..l0+7 -> pA (M=8 tile; rows 8-15 garbage/unused) ---
  {
    f32x4 sap[2];
#pragma unroll
    for (int nt = 0; nt < 2; ++nt) {
      float bv = a2u_b1[colw + nt * 16 + c];
      f32x4 t = {bv, bv, bv, bv};
      sap[nt] = t;
    }
    const float* Xap = h_ap + (size_t)(b * LL + l0) * HH;
#pragma unroll
    for (int ks = 0; ks < 8; ++ks) {
      const int ko = ks * 32 + g * 8;
      bf16x8 a = ld_a8(Xap + (size_t)(c & 7) * HH + ko);
#pragma unroll
      for (int nt = 0; nt < 2; ++nt) {
        bf16x8 bb = ld_a8(a2u_w1 + (size_t)(colw + nt * 16 + c) * 512 + ko);
        sap[nt] = __builtin_amdgcn_mfma_f32_16x16x32_bf16(a, bb, sap[nt], 0, 0, 0);
      }
    }
    if (g < 2) {
#pragma unroll
      for (int nt = 0; nt < 2; ++nt)
#pragma unroll
        for (int rr = 0; rr < 4; ++rr)
          pA[(g * 4 + rr) * 256 + colw + nt * 16 + c] = sap[nt][rr];
    }
  }

  // --- register-resident e-part weights (cvt from f32) ---
  bf16x8 wU[2][8], wA[2][8];
#pragma unroll
  for (int nt = 0; nt < 2; ++nt)
#pragma unroll
    for (int ks = 0; ks < 8; ++ks) {
      size_t off = (size_t)(colw + nt * 16 + c) * 512 + 256 + ks * 32 + g * 8;
      wU[nt][ks] = ld_a8(u2a_w1 + off);
      wA[nt][ks] = ld_a8(a2u_w1 + off);
    }

  wr_tile(ebuf[0], tid, rs);

  f32x4 accU[2][2];
  const f32x4 z4 = {0.f, 0.f, 0.f, 0.f};
#pragma unroll
  for (int m = 0; m < 2; ++m)
#pragma unroll
    for (int nt = 0; nt < 2; ++nt) accU[m][nt] = z4;

  for (int li = 0; li < LGRP; ++li) {
    __syncthreads();                       // ebuf[li&1] + pA visible; prev readers done
    const int l = l0 + li;
    if (li + 1 < LGRP) ld_tile(e + (size_t)((b * LL + l + 1) * KK) * HH, tid, rs);

    f32x4 aU[2][2], aA[2][2];
#pragma unroll
    for (int nt = 0; nt < 2; ++nt) {
      float pa = pA[li * 256 + colw + nt * 16 + c];
      f32x4 t = {pa, pa, pa, pa};
      aA[0][nt] = t; aA[1][nt] = t;
#pragma unroll
      for (int rr = 0; rr < 4; ++rr) {
        aU[0][nt][rr] = pue[0][nt][rr];
        aU[1][nt][rr] = pue[1][nt][rr];
      }
    }
    const bf16_t* eb = ebuf[li & 1];
    const int swz = (c & 7) << 4;
#pragma unroll
    for (int ks = 0; ks < 8; ++ks) {
      const int kb = (ks * 32 + g * 8) * 2;
      bf16x8 a0 = *(const bf16x8*)((const char*)eb + c * 512 + (kb ^ swz));
      bf16x8 a1 = *(const bf16x8*)((const char*)eb + (16 + c) * 512 + (kb ^ swz));
#pragma unroll
      for (int nt = 0; nt < 2; ++nt) {
        aU[0][nt] = __builtin_amdgcn_mfma_f32_16x16x32_bf16(a0, wU[nt][ks], aU[0][nt], 0, 0, 0);
        aU[1][nt] = __builtin_amdgcn_mfma_f32_16x16x32_bf16(a1, wU[nt][ks], aU[1][nt], 0, 0, 0);
        aA[0][nt] = __builtin_amdgcn_mfma_f32_16x16x32_bf16(a0, wA[nt][ks], aA[0][nt], 0, 0, 0);
        aA[1][nt] = __builtin_amdgcn_mfma_f32_16x16x32_bf16(a1, wA[nt][ks], aA[1][nt], 0, 0, 0);
      }
    }
    __syncthreads();                       // ebuf[li&1] reads done
    if (li + 1 < LGRP) wr_tile(ebuf[(li + 1) & 1], tid, rs);

    // u2a: relu + k-reduce -> R_ap[b,l,:]  (no bias; /K folded at node m-GEMM)
#pragma unroll
    for (int nt = 0; nt < 2; ++nt) {
      float s = 0.f;
#pragma unroll
      for (int m = 0; m < 2; ++m)
#pragma unroll
        for (int rr = 0; rr < 4; ++rr) s += fmaxf(aU[m][nt][rr], 0.f);
      s += __shfl_xor(s, 16);
      s += __shfl_xor(s, 32);
      if (lane < 16)
        R_ap[(size_t)(b * LL + l) * HH + colw + nt * 16 + lane] = s;
    }
    // a2u: relu accumulate over l
#pragma unroll
    for (int m = 0; m < 2; ++m)
#pragma unroll
      for (int nt = 0; nt < 2; ++nt)
#pragma unroll
        for (int rr = 0; rr < 4; ++rr)
          accU[m][nt][rr] += fmaxf(aA[m][nt][rr], 0.f);
  }

#pragma unroll
  for (int m = 0; m < 2; ++m)
#pragma unroll
    for (int nt = 0; nt < 2; ++nt)
#pragma unroll
      for (int rr = 0; rr < 4; ++rr) {
        int krow = m * 16 + g * 4 + rr;
        part[(size_t)((lc * BB + b) * KK + krow) * HH + colw + nt * 16 + c] = accU[m][nt][rr];
      }
}

// ============ node: reduce + layer-2 msg GEMM + GRU (both node types) ============
__global__ __launch_bounds__(256) void node_kernel(
    const float* __restrict__ part, const float* __restrict__ R_ap,
    const float* __restrict__ a2u_w2, const float* __restrict__ a2u_b2,
    const float* __restrict__ u2a_w2, const float* __restrict__ u2a_b2,
    const float* __restrict__ h_ue, const float* __restrict__ ue_wih,
    const float* __restrict__ ue_bih, const float* __restrict__ ue_whh,
    const float* __restrict__ ue_bhh,
    const float* __restrict__ h_ap, const float* __restrict__ ap_wih,
    const float* __restrict__ ap_bih, const float* __restrict__ ap_whh,
    const float* __restrict__ ap_bhh,
    float* __restrict__ hue_new, float* __restrict__ hap_new) {
  __shared__ bf16_t mbuf[32 * 256];
  const int blk = blockIdx.x;              // 192 blocks: 64 UE + 128 AP
  const bool ue = blk < 64;
  const int row0 = ue ? blk * 32 : (blk - 64) * 32;
  const int tid = threadIdx.x, w = tid >> 6, lane = tid & 63;
  const int colw = w * 64, c = lane & 15, g = lane >> 4;
  const float* W2  = ue ? a2u_w2 : u2a_w2;
  const float* b2  = ue ? a2u_b2 : u2a_b2;
  const float* h   = ue ? h_ue : h_ap;
  const float* wih = ue ? ue_wih : ap_wih;
  const float* whh = ue ? ue_whh : ap_whh;
  const float* bih = ue ? ue_bih : ap_bih;
  const float* bhh = ue ? ue_bhh : ap_bhh;
  float* hout      = ue ? hue_new : hap_new;
  const float sc   = ue ? (1.f / 64.f) : (1.f / 32.f);   // /L or /K

  // --- m = R*(W2*sc)^T + b2 ---
  f32x4 acc[2][4];
#pragma unroll
  for (int nt = 0; nt < 4; ++nt) {
    float bv = b2[colw + nt * 16 + c];
    f32x4 t = {bv, bv, bv, bv};
    acc[0][nt] = t; acc[1][nt] = t;
  }
  if (ue) mm_partA(part + (size_t)row0 * HH, W2 + (size_t)colw * HH, acc, lane, sc);
  else    mm_f32AB<HH>(R_ap + (size_t)row0 * HH, W2 + (size_t)colw * HH, acc, lane, sc);

  // m -> swizzled bf16 LDS (no relu)
#pragma unroll
  for (int m = 0; m < 2; ++m)
#pragma unroll
    for (int nt = 0; nt < 4; ++nt)
#pragma unroll
      for (int rr = 0; rr < 4; ++rr) {
        int row = m * 16 + g * 4 + rr;
        int col = colw + nt * 16 + c;
        int off = row * 512 + ((col * 2) ^ ((row & 7) << 4));
        *(bf16_t*)((char*)mbuf + off) = (__bf16)acc[m][nt][rr];
      }
  __syncthreads();

  // --- GRU ---
  f32x4 aR[2][4], aZ[2][4], aN[2][4], aHN[2][4];
#pragma unroll
  for (int nt = 0; nt < 4; ++nt) {
    int col = colw + nt * 16 + c;
    float vR = bih[col] + bhh[col];
    float vZ = bih[256 + col] + bhh[256 + col];
    float vN = bih[512 + col];
    float vH = bhh[512 + col];
    f32x4 tR = {vR, vR, vR, vR}, tZ = {vZ, vZ, vZ, vZ};
    f32x4 tN = {vN, vN, vN, vN}, tH = {vH, vH, vH, vH};
    aR[0][nt] = tR; aR[1][nt] = tR;
    aZ[0][nt] = tZ; aZ[1][nt] = tZ;
    aN[0][nt] = tN; aN[1][nt] = tN;
    aHN[0][nt] = tH; aHN[1][nt] = tH;
  }
  const float* Hp = h + (size_t)row0 * HH;
  mm_lds_f32B(mbuf, wih + (size_t)(0   + colw) * HH, aR, lane);
  mm_f32AB<HH>(Hp,  whh + (size_t)(0   + colw) * HH, aR, lane, 1.f);
  mm_lds_f32B(mbuf, wih + (size_t)(256 + colw) * HH, aZ, lane);
  mm_f32AB<HH>(Hp,  whh + (size_t)(256 + colw) * HH, aZ, lane, 1.f);
  mm_lds_f32B(mbuf, wih + (size_t)(512 + colw) * HH, aN, lane);
  mm_f32AB<HH>(Hp,  whh + (size_t)(512 + colw) * HH, aHN, lane, 1.f);
#pragma unroll
  for (int m = 0; m < 2; ++m)
#pragma unroll
    for (int nt = 0; nt < 4; ++nt)
#pragma unroll
      for (int rr = 0; rr < 4; ++rr) {
        int row = row0 + m * 16 + g * 4 + rr;
        int col = colw + nt * 16 + c;
        float rg = 1.f / (1.f + __expf(-aR[m][nt][rr]));
        float zg = 1.f / (1.f + __expf(-aZ[m][nt][rr]));
        float t = aN[m][nt][rr] + rg * aHN[m][nt][rr];
        t = fminf(fmaxf(t, -15.f), 15.f);
        float ex = __expf(-2.f * t);
        float ng = (1.f - ex) / (1.f + ex);
        float ho = h[(size_t)row * HH + col];
        hout[(size_t)row * HH + col] = (1.f - zg) * ng + zg * ho;
      }
}

// ============ phase C: q_ue/q_ap in-kernel + edge-update MLP ============
__global__ __launch_bounds__(512) void phaseC_kernel(
    const float* __restrict__ e, const float* __restrict__ hue_new,
    const float* __restrict__ hap_new,
    const float* __restrict__ ed_w1, const float* __restrict__ ed_b1,
    const float* __restrict__ ed_w2, const float* __restrict__ ed_b2,
    float* __restrict__ e_new) {
  __shared__ bf16_t ebuf[2][32 * 256];
  __shared__ bf16_t pbuf[32 * 256];
  __shared__ float qA[8 * 256];
  const int blk = blockIdx.x;              // 512 blocks
  const int b = blk >> 3, lc = blk & 7;
  const int tid = threadIdx.x, w = tid >> 6, lane = tid & 63;
  const int colw = w * 32, c = lane & 15, g = lane >> 4;
  const int l0 = lc * LGRP;

  f32x4 rs[4];
  ld_tile(e + (size_t)((b * LL + l0) * KK) * HH, tid, rs);

  // --- q_ue = hue_new[b]*Wed1[:, :H]^T + ed_b1 (register-direct) ---
  float qU[2][2][4];
  {
    f32x4 qacc[2][2];
#pragma unroll
    for (int nt = 0; nt < 2; ++nt) {
      float bv = ed_b1[colw + nt * 16 + c];
      f32x4 t = {bv, bv, bv, bv};
      qacc[0][nt] = t; qacc[1][nt] = t;
    }
#pragma unroll
    for (int ks = 0; ks < 8; ++ks) {
      const int ko = ks * 32 + g * 8;
      bf16x8 a0 = ld_a8(hue_new + (size_t)(b * KK + c) * HH + ko);
      bf16x8 a1 = ld_a8(hue_new + (size_t)(b * KK + 16 + c) * HH + ko);
#pragma unroll
      for (int nt = 0; nt < 2; ++nt) {
        bf16x8 bb = ld_a8(ed_w1 + (size_t)(colw + nt * 16 + c) * 768 + ko);
        qacc[0][nt] = __builtin_amdgcn_mfma_f32_16x16x32_bf16(a0, bb, qacc[0][nt], 0, 0, 0);
        qacc[1][nt] = __builtin_amdgcn_mfma_f32_16x16x32_bf16(a1, bb, qacc[1][nt], 0, 0, 0);
      }
    }
#pragma unroll
    for (int m = 0; m < 2; ++m)
#pragma unroll
      for (int nt = 0; nt < 2; ++nt)
#pragma unroll
        for (int rr = 0; rr < 4; ++rr) qU[m][nt][rr] = qacc[m][nt][rr];
  }

  // --- q_ap rows l0..l0+7 -> qA (no bias) ---
  {
    f32x4 sap[2];
    const f32x4 z4 = {0.f, 0.f, 0.f, 0.f};
    sap[0] = z4; sap[1] = z4;
    const float* Xap = hap_new + (size_t)(b * LL + l0) * HH;
#pragma unroll
    for (int ks = 0; ks < 8; ++ks) {
      const int ko = ks * 32 + g * 8;
      bf16x8 a = ld_a8(Xap + (size_t)(c & 7) * HH + ko);
#pragma unroll
      for (int nt = 0; nt < 2; ++nt) {
        bf16x8 bb = ld_a8(ed_w1 + (size_t)(colw + nt * 16 + c) * 768 + 256 + ko);
        sap[nt] = __builtin_amdgcn_mfma_f32_16x16x32_bf16(a, bb, sap[nt], 0, 0, 0);
      }
    }
    if (g < 2) {
#pragma unroll
      for (int nt = 0; nt < 2; ++nt)
#pragma unroll
        for (int rr = 0; rr < 4; ++rr)
          qA[(g * 4 + rr) * 256 + colw + nt * 16 + c] = sap[nt][rr];
    }
  }

  // --- register weights ---
  bf16x8 w1[2][8], w2[2][8];
#pragma unroll
  for (int nt = 0; nt < 2; ++nt)
#pragma unroll
    for (int ks = 0; ks < 8; ++ks) {
      w1[nt][ks] = ld_a8(ed_w1 + (size_t)(colw + nt * 16 + c) * 768 + 512 + ks * 32 + g * 8);
      w2[nt][ks] = ld_a8(ed_w2 + (size_t)(colw + nt * 16 + c) * 256 + ks * 32 + g * 8);
    }
  float b2v[2];
#pragma unroll
  for (int nt = 0; nt < 2; ++nt) b2v[nt] = ed_b2[colw + nt * 16 + c];

  wr_tile(ebuf[0], tid, rs);

  for (int li = 0; li < LGRP; ++li) {
    __syncthreads();                       // ebuf[li&1]+qA visible; prev pbuf readers done
    const int l = l0 + li;

    f32x4 a1[2][2];
#pragma unroll
    for (int nt = 0; nt < 2; ++nt) {
      float qa = qA[li * 256 + colw + nt * 16 + c];
#pragma unroll
      for (int rr = 0; rr < 4; ++rr) {
        a1[0][nt][rr] = qa + qU[0][nt][rr];
        a1[1][nt][rr] = qa + qU[1][nt][rr];
      }
    }
    const bf16_t* eb = ebuf[li & 1];
    const int swz = (c & 7) << 4;
#pragma unroll
    for (int ks = 0; ks < 8; ++ks) {
      const int kb = (ks * 32 + g * 8) * 2;
      bf16x8 a0 = *(const bf16x8*)((const char*)eb + c * 512 + (kb ^ swz));
      bf16x8 a1f = *(const bf16x8*)((const char*)eb + (16 + c) * 512 + (kb ^ swz));
#pragma unroll
      for (int nt = 0; nt < 2; ++nt) {
        a1[0][nt] = __builtin_amdgcn_mfma_f32_16x16x32_bf16(a0,  w1[nt][ks], a1[0][nt], 0, 0, 0);
        a1[1][nt] = __builtin_amdgcn_mfma_f32_16x16x32_bf16(a1f, w1[nt][ks], a1[1][nt], 0, 0, 0);
      }
    }
    if (li + 1 < LGRP) ld_tile(e + (size_t)((b * LL + l + 1) * KK) * HH, tid, rs);

    // relu -> pbuf
#pragma unroll
    for (int m = 0; m < 2; ++m)
#pragma unroll
      for (int nt = 0; nt < 2; ++nt)
#pragma unroll
        for (int rr = 0; rr < 4; ++rr) {
          int row = m * 16 + g * 4 + rr;
          int col = colw + nt * 16 + c;
          float v = fmaxf(a1[m][nt][rr], 0.f);
          int off = row * 512 + ((col * 2) ^ ((row & 7) << 4));
          *(bf16_t*)((char*)pbuf + off) = (__bf16)v;
        }
    __syncthreads();                       // pbuf visible

    f32x4 a2[2][2];
#pragma unroll
    for (int nt = 0; nt < 2; ++nt) {
      f32x4 t = {b2v[nt], b2v[nt], b2v[nt], b2v[nt]};
      a2[0][nt] = t; a2[1][nt] = t;
    }
#pragma unroll
    for (int ks = 0; ks < 8; ++ks) {
      const int kb = (ks * 32 + g * 8) * 2;
      bf16x8 a0 = *(const bf16x8*)((const char*)pbuf + c * 512 + (kb ^ swz));
      bf16x8 a1f = *(const bf16x8*)((const char*)pbuf + (16 + c) * 512 + (kb ^ swz));
#pragma unroll
      for (int nt = 0; nt < 2; ++nt) {
        a2[0][nt] = __builtin_amdgcn_mfma_f32_16x16x32_bf16(a0,  w2[nt][ks], a2[0][nt], 0, 0, 0);
        a2[1][nt] = __builtin_amdgcn_mfma_f32_16x16x32_bf16(a1f, w2[nt][ks], a2[1][nt], 0, 0, 0);
      }
    }
#pragma unroll
    for (int m = 0; m < 2; ++m)
#pragma unroll
      for (int nt = 0; nt < 2; ++nt)
#pragma unroll
        for (int rr = 0; rr < 4; ++rr) {
          int row = m * 16 + g * 4 + rr;
          e_new[(size_t)((b * LL + l) * KK + row) * HH + colw + nt * 16 + c] = a2[m][nt][rr];
        }
    if (li + 1 < LGRP) wr_tile(ebuf[(li + 1) & 1], tid, rs);
  }
}

extern "C" void kernel_launch(void* const* d_in, const int* in_sizes, int n_in,
                              void* d_out, int out_size, void* d_ws, size_t ws_size,
                              hipStream_t stream) {
  const float* h_ue   = (const float*)d_in[0];
  const float* h_ap   = (const float*)d_in[1];
  const float* e      = (const float*)d_in[2];
  const float* a2u_w1 = (const float*)d_in[3];
  const float* a2u_b1 = (const float*)d_in[4];
  const float* a2u_w2 = (const float*)d_in[5];
  const float* a2u_b2 = (const float*)d_in[6];
  const float* u2a_w1 = (const float*)d_in[7];
  const float* u2a_b1 = (const float*)d_in[8];
  const float* u2a_w2 = (const float*)d_in[9];
  const float* u2a_b2 = (const float*)d_in[10];
  const float* ue_wih = (const float*)d_in[11];
  const float* ue_bih = (const float*)d_in[12];
  const float* ue_whh = (const float*)d_in[13];
  const float* ue_bhh = (const float*)d_in[14];
  const float* ap_wih = (const float*)d_in[15];
  const float* ap_bih = (const float*)d_in[16];
  const float* ap_whh = (const float*)d_in[17];
  const float* ap_bhh = (const float*)d_in[18];
  const float* ed_w1  = (const float*)d_in[19];
  const float* ed_b1  = (const float*)d_in[20];
  const float* ed_w2  = (const float*)d_in[21];
  const float* ed_b2  = (const float*)d_in[22];

  float* part = (float*)d_ws;           // 8 * 524288 f32
  float* R_ap = part + 4194304;         // 1048576 f32

  float* out      = (float*)d_out;
  float* hue_new  = out;                // 524288
  float* hap_new  = out + 524288;       // 1048576
  float* e_new    = out + 1572864;      // 33554432

  phaseA_kernel<<<512, 512, 0, stream>>>(e, h_ue, h_ap,
                                         a2u_w1, a2u_b1, u2a_w1, u2a_b1,
                                         part, R_ap);
  node_kernel<<<192, 256, 0, stream>>>(part, R_ap,
                                       a2u_w2, a2u_b2, u2a_w2, u2a_b2,
                                       h_ue, ue_wih, ue_bih, ue_whh, ue_bhh,
                                       h_ap, ap_wih, ap_bih, ap_whh, ap_bhh,
                                       hue_new, hap_new);
  phaseC_kernel<<<512, 512, 0, stream>>>(e, hue_new, hap_new,
                                         ed_w1, ed_b1, ed_w2, ed_b2, e_new);
}

// Round 6
// 332.634 us; speedup vs baseline: 1.0146x; 1.0146x over previous
//
#include <hip/hip_runtime.h>

#define HH 256   // H
#define BB 64    // B
#define KK 32    // K
#define LL 64    // L
#define LGRP 8   // l's per edge-kernel block

typedef __bf16 bf16_t;
typedef __attribute__((ext_vector_type(8))) __bf16 bf16x8;
typedef __attribute__((ext_vector_type(4))) float f32x4;

// ---- load 8 contiguous f32 -> bf16x8 ----
__device__ __forceinline__ bf16x8 ld_a8(const float* __restrict__ p) {
  const f32x4* q = (const f32x4*)p;
  f32x4 a = q[0], b = q[1];
  bf16x8 r;
  r[0] = (__bf16)a[0]; r[1] = (__bf16)a[1]; r[2] = (__bf16)a[2]; r[3] = (__bf16)a[3];
  r[4] = (__bf16)b[0]; r[5] = (__bf16)b[1]; r[6] = (__bf16)b[2]; r[7] = (__bf16)b[3];
  return r;
}
__device__ __forceinline__ bf16x8 ld_a8s(const float* __restrict__ p, float sc) {
  const f32x4* q = (const f32x4*)p;
  f32x4 a = q[0], b = q[1];
  bf16x8 r;
  r[0] = (__bf16)(a[0]*sc); r[1] = (__bf16)(a[1]*sc); r[2] = (__bf16)(a[2]*sc); r[3] = (__bf16)(a[3]*sc);
  r[4] = (__bf16)(b[0]*sc); r[5] = (__bf16)(b[1]*sc); r[6] = (__bf16)(b[2]*sc); r[7] = (__bf16)(b[3]*sc);
  return r;
}
// sum 8 partial slices (stride 524288 f32) -> bf16x8
__device__ __forceinline__ bf16x8 ld_sum8(const float* __restrict__ p) {
  f32x4 s0 = {0.f,0.f,0.f,0.f}, s1 = s0;
#pragma unroll
  for (int lc = 0; lc < 8; ++lc) {
    const f32x4* q = (const f32x4*)(p + (size_t)lc * 524288);
    s0 += q[0]; s1 += q[1];
  }
  bf16x8 r;
  r[0] = (__bf16)s0[0]; r[1] = (__bf16)s0[1]; r[2] = (__bf16)s0[2]; r[3] = (__bf16)s0[3];
  r[4] = (__bf16)s1[0]; r[5] = (__bf16)s1[1]; r[6] = (__bf16)s1[2]; r[7] = (__bf16)s1[3];
  return r;
}

// ---- e-tile staging (512 threads): 16 f32/thread -> regs -> swizzled bf16 LDS ----
__device__ __forceinline__ void ld_tile(const float* __restrict__ E, int tid, f32x4 r[4]) {
  const f32x4* q = (const f32x4*)(E + tid * 16);
  r[0] = q[0]; r[1] = q[1]; r[2] = q[2]; r[3] = q[3];
}
__device__ __forceinline__ void wr_tile(bf16_t* buf, int tid, const f32x4 r[4]) {
  int row = tid >> 4;
  int colb = (tid & 15) * 32;
  bf16x8 v0, v1;
  v0[0] = (__bf16)r[0][0]; v0[1] = (__bf16)r[0][1]; v0[2] = (__bf16)r[0][2]; v0[3] = (__bf16)r[0][3];
  v0[4] = (__bf16)r[1][0]; v0[5] = (__bf16)r[1][1]; v0[6] = (__bf16)r[1][2]; v0[7] = (__bf16)r[1][3];
  v1[0] = (__bf16)r[2][0]; v1[1] = (__bf16)r[2][1]; v1[2] = (__bf16)r[2][2]; v1[3] = (__bf16)r[2][3];
  v1[4] = (__bf16)r[3][0]; v1[5] = (__bf16)r[3][1]; v1[6] = (__bf16)r[3][2]; v1[7] = (__bf16)r[3][3];
  int swz = (row & 7) << 4;
  *(bf16x8*)((char*)buf + row * 512 + (colb ^ swz)) = v0;
  *(bf16x8*)((char*)buf + row * 512 + ((colb + 16) ^ swz)) = v1;
}

// acc[2][4] += A(32x256 f32 global)*B(f32 global, cvt+scale)^T  (4-wave, 64-col wave)
template<int LDB>
__device__ __forceinline__ void mm_f32AB(const float* __restrict__ A,
                                         const float* __restrict__ B,
                                         f32x4 acc[2][4], int lane, float sc) {
  const int c = lane & 15, g = lane >> 4;
#pragma unroll
  for (int ks = 0; ks < 8; ++ks) {
    const int ko = ks * 32 + g * 8;
    bf16x8 a0 = ld_a8(A + (size_t)c * HH + ko);
    bf16x8 a1 = ld_a8(A + (size_t)(16 + c) * HH + ko);
#pragma unroll
    for (int nt = 0; nt < 4; ++nt) {
      bf16x8 bb = ld_a8s(B + (size_t)(nt * 16 + c) * LDB + ko, sc);
      acc[0][nt] = __builtin_amdgcn_mfma_f32_16x16x32_bf16(a0, bb, acc[0][nt], 0, 0, 0);
      acc[1][nt] = __builtin_amdgcn_mfma_f32_16x16x32_bf16(a1, bb, acc[1][nt], 0, 0, 0);
    }
  }
}

// acc[2][4] += (Σ_lc part)(32x256)*B^T  — UE message reduce fused into A-fragments
__device__ __forceinline__ void mm_partA(const float* __restrict__ P,
                                         const float* __restrict__ B,
                                         f32x4 acc[2][4], int lane, float sc) {
  const int c = lane & 15, g = lane >> 4;
#pragma unroll
  for (int ks = 0; ks < 8; ++ks) {
    const int ko = ks * 32 + g * 8;
    bf16x8 a0 = ld_sum8(P + (size_t)c * HH + ko);
    bf16x8 a1 = ld_sum8(P + (size_t)(16 + c) * HH + ko);
#pragma unroll
    for (int nt = 0; nt < 4; ++nt) {
      bf16x8 bb = ld_a8s(B + (size_t)(nt * 16 + c) * HH + ko, sc);
      acc[0][nt] = __builtin_amdgcn_mfma_f32_16x16x32_bf16(a0, bb, acc[0][nt], 0, 0, 0);
      acc[1][nt] = __builtin_amdgcn_mfma_f32_16x16x32_bf16(a1, bb, acc[1][nt], 0, 0, 0);
    }
  }
}

// acc[2][4] += LDS(32x256 bf16 swizzled)*B(f32 global cvt)^T
__device__ __forceinline__ void mm_lds_f32B(const bf16_t* lds,
                                            const float* __restrict__ B,
                                            f32x4 acc[2][4], int lane) {
  const int c = lane & 15, g = lane >> 4;
  const int swz = (c & 7) << 4;
#pragma unroll
  for (int ks = 0; ks < 8; ++ks) {
    const int kb = (ks * 32 + g * 8) * 2;
    bf16x8 a0 = *(const bf16x8*)((const char*)lds + c * 512 + (kb ^ swz));
    bf16x8 a1 = *(const bf16x8*)((const char*)lds + (16 + c) * 512 + (kb ^ swz));
#pragma unroll
    for (int nt = 0; nt < 4; ++nt) {
      bf16x8 bb = ld_a8(B + (size_t)(nt * 16 + c) * HH + ks * 32 + g * 8);
      acc[0][nt] = __builtin_amdgcn_mfma_f32_16x16x32_bf16(a0, bb, acc[0][nt], 0, 0, 0);
      acc[1][nt] = __builtin_amdgcn_mfma_f32_16x16x32_bf16(a1, bb, acc[1][nt], 0, 0, 0);
    }
  }
}

// ============ phase A: p_ue/p_ap in-kernel + layer-1 of both MLPs + reductions ============
// __launch_bounds__(512, 2): 8 waves/block = 2 waves/EU -> 256-VGPR cap. The register-
// resident weight set (wU+wA = 128 VGPRs) + accumulators needs ~240; without this pin the
// compiler picked 128 and spilled (R5: WRITE_SIZE +11MB, 138us).
__global__ __launch_bounds__(512, 2) void phaseA_kernel(
    const float* __restrict__ e, const float* __restrict__ h_ue,
    const float* __restrict__ h_ap,
    const float* __restrict__ a2u_w1, const float* __restrict__ a2u_b1,
    const float* __restrict__ u2a_w1, const float* __restrict__ u2a_b1,
    float* __restrict__ part, float* __restrict__ R_ap) {
  __shared__ bf16_t ebuf[2][32 * 256];
  __shared__ float pA[8 * 256];
  const int blk = blockIdx.x;              // 512 blocks
  const int b = blk >> 3, lc = blk & 7;
  const int tid = threadIdx.x, w = tid >> 6, lane = tid & 63;
  const int colw = w * 32, c = lane & 15, g = lane >> 4;
  const int l0 = lc * LGRP;

  // issue first e tile loads early
  f32x4 rs[4];
  ld_tile(e + (size_t)((b * LL + l0) * KK) * HH, tid, rs);

  // --- prologue 1: p_ue = h_ue[b]*Wu1_h^T + u2a_b1 (register-direct layout) ---
  float pue[2][2][4];
  {
    f32x4 pacc[2][2];
#pragma unroll
    for (int nt = 0; nt < 2; ++nt) {
      float bv = u2a_b1[colw + nt * 16 + c];
      f32x4 t = {bv, bv, bv, bv};
      pacc[0][nt] = t; pacc[1][nt] = t;
    }
#pragma unroll
    for (int ks = 0; ks < 8; ++ks) {
      const int ko = ks * 32 + g * 8;
      bf16x8 a0 = ld_a8(h_ue + (size_t)(b * KK + c) * HH + ko);
      bf16x8 a1 = ld_a8(h_ue + (size_t)(b * KK + 16 + c) * HH + ko);
#pragma unroll
      for (int nt = 0; nt < 2; ++nt) {
        bf16x8 bb = ld_a8(u2a_w1 + (size_t)(colw + nt * 16 + c) * 512 + ko);
        pacc[0][nt] = __builtin_amdgcn_mfma_f32_16x16x32_bf16(a0, bb, pacc[0][nt], 0, 0, 0);
        pacc[1][nt] = __builtin_amdgcn_mfma_f32_16x16x32_bf16(a1, bb, pacc[1][nt], 0, 0, 0);
      }
    }
#pragma unroll
    for (int m = 0; m < 2; ++m)
#pragma unroll
      for (int nt = 0; nt < 2; ++nt)
#pragma unroll
        for (int rr = 0; rr < 4; ++rr) pue[m][nt][rr] = pacc[m][nt][rr];
  }

  // --- prologue 2: p_ap rows l0..l0+7 -> pA (M=8 tile; rows 8-15 garbage/unused) ---
  {
    f32x4 sap[2];
#pragma unroll
    for (int nt = 0; nt < 2; ++nt) {
      float bv = a2u_b1[colw + nt * 16 + c];
      f32x4 t = {bv, bv, bv, bv};
      sap[nt] = t;
    }
    const float* Xap = h_ap + (size_t)(b * LL + l0) * HH;
#pragma unroll
    for (int ks = 0; ks < 8; ++ks) {
      const int ko = ks * 32 + g * 8;
      bf16x8 a = ld_a8(Xap + (size_t)(c & 7) * HH + ko);
#pragma unroll
      for (int nt = 0; nt < 2; ++nt) {
        bf16x8 bb = ld_a8(a2u_w1 + (size_t)(colw + nt * 16 + c) * 512 + ko);
        sap[nt] = __builtin_amdgcn_mfma_f32_16x16x32_bf16(a, bb, sap[nt], 0, 0, 0);
      }
    }
    if (g < 2) {
#pragma unroll
      for (int nt = 0; nt < 2; ++nt)
#pragma unroll
        for (int rr = 0; rr < 4; ++rr)
          pA[(g * 4 + rr) * 256 + colw + nt * 16 + c] = sap[nt][rr];
    }
  }

  // --- register-resident e-part weights (cvt from f32) ---
  bf16x8 wU[2][8], wA[2][8];
#pragma unroll
  for (int nt = 0; nt < 2; ++nt)
#pragma unroll
    for (int ks = 0; ks < 8; ++ks) {
      size_t off = (size_t)(colw + nt * 16 + c) * 512 + 256 + ks * 32 + g * 8;
      wU[nt][ks] = ld_a8(u2a_w1 + off);
      wA[nt][ks] = ld_a8(a2u_w1 + off);
    }

  wr_tile(ebuf[0], tid, rs);

  f32x4 accU[2][2];
  const f32x4 z4 = {0.f, 0.f, 0.f, 0.f};
#pragma unroll
  for (int m = 0; m < 2; ++m)
#pragma unroll
    for (int nt = 0; nt < 2; ++nt) accU[m][nt] = z4;

  for (int li = 0; li < LGRP; ++li) {
    __syncthreads();                       // ebuf[li&1] + pA visible; prev readers done
    const int l = l0 + li;
    if (li + 1 < LGRP) ld_tile(e + (size_t)((b * LL + l + 1) * KK) * HH, tid, rs);

    f32x4 aU[2][2], aA[2][2];
#pragma unroll
    for (int nt = 0; nt < 2; ++nt) {
      float pa = pA[li * 256 + colw + nt * 16 + c];
      f32x4 t = {pa, pa, pa, pa};
      aA[0][nt] = t; aA[1][nt] = t;
#pragma unroll
      for (int rr = 0; rr < 4; ++rr) {
        aU[0][nt][rr] = pue[0][nt][rr];
        aU[1][nt][rr] = pue[1][nt][rr];
      }
    }
    const bf16_t* eb = ebuf[li & 1];
    const int swz = (c & 7) << 4;
#pragma unroll
    for (int ks = 0; ks < 8; ++ks) {
      const int kb = (ks * 32 + g * 8) * 2;
      bf16x8 a0 = *(const bf16x8*)((const char*)eb + c * 512 + (kb ^ swz));
      bf16x8 a1 = *(const bf16x8*)((const char*)eb + (16 + c) * 512 + (kb ^ swz));
#pragma unroll
      for (int nt = 0; nt < 2; ++nt) {
        aU[0][nt] = __builtin_amdgcn_mfma_f32_16x16x32_bf16(a0, wU[nt][ks], aU[0][nt], 0, 0, 0);
        aU[1][nt] = __builtin_amdgcn_mfma_f32_16x16x32_bf16(a1, wU[nt][ks], aU[1][nt], 0, 0, 0);
        aA[0][nt] = __builtin_amdgcn_mfma_f32_16x16x32_bf16(a0, wA[nt][ks], aA[0][nt], 0, 0, 0);
        aA[1][nt] = __builtin_amdgcn_mfma_f32_16x16x32_bf16(a1, wA[nt][ks], aA[1][nt], 0, 0, 0);
      }
    }
    __syncthreads();                       // ebuf[li&1] reads done
    if (li + 1 < LGRP) wr_tile(ebuf[(li + 1) & 1], tid, rs);

    // u2a: relu + k-reduce -> R_ap[b,l,:]  (no bias; /K folded at node m-GEMM)
#pragma unroll
    for (int nt = 0; nt < 2; ++nt) {
      float s = 0.f;
#pragma unroll
      for (int m = 0; m < 2; ++m)
#pragma unroll
        for (int rr = 0; rr < 4; ++rr) s += fmaxf(aU[m][nt][rr], 0.f);
      s += __shfl_xor(s, 16);
      s += __shfl_xor(s, 32);
      if (lane < 16)
        R_ap[(size_t)(b * LL + l) * HH + colw + nt * 16 + lane] = s;
    }
    // a2u: relu accumulate over l
#pragma unroll
    for (int m = 0; m < 2; ++m)
#pragma unroll
      for (int nt = 0; nt < 2; ++nt)
#pragma unroll
        for (int rr = 0; rr < 4; ++rr)
          accU[m][nt][rr] += fmaxf(aA[m][nt][rr], 0.f);
  }

#pragma unroll
  for (int m = 0; m < 2; ++m)
#pragma unroll
    for (int nt = 0; nt < 2; ++nt)
#pragma unroll
      for (int rr = 0; rr < 4; ++rr) {
        int krow = m * 16 + g * 4 + rr;
        part[(size_t)((lc * BB + b) * KK + krow) * HH + colw + nt * 16 + c] = accU[m][nt][rr];
      }
}

// ============ node: reduce + layer-2 msg GEMM + GRU (both node types) ============
__global__ __launch_bounds__(256) void node_kernel(
    const float* __restrict__ part, const float* __restrict__ R_ap,
    const float* __restrict__ a2u_w2, const float* __restrict__ a2u_b2,
    const float* __restrict__ u2a_w2, const float* __restrict__ u2a_b2,
    const float* __restrict__ h_ue, const float* __restrict__ ue_wih,
    const float* __restrict__ ue_bih, const float* __restrict__ ue_whh,
    const float* __restrict__ ue_bhh,
    const float* __restrict__ h_ap, const float* __restrict__ ap_wih,
    const float* __restrict__ ap_bih, const float* __restrict__ ap_whh,
    const float* __restrict__ ap_bhh,
    float* __restrict__ hue_new, float* __restrict__ hap_new) {
  __shared__ bf16_t mbuf[32 * 256];
  const int blk = blockIdx.x;              // 192 blocks: 64 UE + 128 AP
  const bool ue = blk < 64;
  const int row0 = ue ? blk * 32 : (blk - 64) * 32;
  const int tid = threadIdx.x, w = tid >> 6, lane = tid & 63;
  const int colw = w * 64, c = lane & 15, g = lane >> 4;
  const float* W2  = ue ? a2u_w2 : u2a_w2;
  const float* b2  = ue ? a2u_b2 : u2a_b2;
  const float* h   = ue ? h_ue : h_ap;
  const float* wih = ue ? ue_wih : ap_wih;
  const float* whh = ue ? ue_whh : ap_whh;
  const float* bih = ue ? ue_bih : ap_bih;
  const float* bhh = ue ? ue_bhh : ap_bhh;
  float* hout      = ue ? hue_new : hap_new;
  const float sc   = ue ? (1.f / 64.f) : (1.f / 32.f);   // /L or /K

  // --- m = R*(W2*sc)^T + b2 ---
  f32x4 acc[2][4];
#pragma unroll
  for (int nt = 0; nt < 4; ++nt) {
    float bv = b2[colw + nt * 16 + c];
    f32x4 t = {bv, bv, bv, bv};
    acc[0][nt] = t; acc[1][nt] = t;
  }
  if (ue) mm_partA(part + (size_t)row0 * HH, W2 + (size_t)colw * HH, acc, lane, sc);
  else    mm_f32AB<HH>(R_ap + (size_t)row0 * HH, W2 + (size_t)colw * HH, acc, lane, sc);

  // m -> swizzled bf16 LDS (no relu)
#pragma unroll
  for (int m = 0; m < 2; ++m)
#pragma unroll
    for (int nt = 0; nt < 4; ++nt)
#pragma unroll
      for (int rr = 0; rr < 4; ++rr) {
        int row = m * 16 + g * 4 + rr;
        int col = colw + nt * 16 + c;
        int off = row * 512 + ((col * 2) ^ ((row & 7) << 4));
        *(bf16_t*)((char*)mbuf + off) = (__bf16)acc[m][nt][rr];
      }
  __syncthreads();

  // --- GRU ---
  f32x4 aR[2][4], aZ[2][4], aN[2][4], aHN[2][4];
#pragma unroll
  for (int nt = 0; nt < 4; ++nt) {
    int col = colw + nt * 16 + c;
    float vR = bih[col] + bhh[col];
    float vZ = bih[256 + col] + bhh[256 + col];
    float vN = bih[512 + col];
    float vH = bhh[512 + col];
    f32x4 tR = {vR, vR, vR, vR}, tZ = {vZ, vZ, vZ, vZ};
    f32x4 tN = {vN, vN, vN, vN}, tH = {vH, vH, vH, vH};
    aR[0][nt] = tR; aR[1][nt] = tR;
    aZ[0][nt] = tZ; aZ[1][nt] = tZ;
    aN[0][nt] = tN; aN[1][nt] = tN;
    aHN[0][nt] = tH; aHN[1][nt] = tH;
  }
  const float* Hp = h + (size_t)row0 * HH;
  mm_lds_f32B(mbuf, wih + (size_t)(0   + colw) * HH, aR, lane);
  mm_f32AB<HH>(Hp,  whh + (size_t)(0   + colw) * HH, aR, lane, 1.f);
  mm_lds_f32B(mbuf, wih + (size_t)(256 + colw) * HH, aZ, lane);
  mm_f32AB<HH>(Hp,  whh + (size_t)(256 + colw) * HH, aZ, lane, 1.f);
  mm_lds_f32B(mbuf, wih + (size_t)(512 + colw) * HH, aN, lane);
  mm_f32AB<HH>(Hp,  whh + (size_t)(512 + colw) * HH, aHN, lane, 1.f);
#pragma unroll
  for (int m = 0; m < 2; ++m)
#pragma unroll
    for (int nt = 0; nt < 4; ++nt)
#pragma unroll
      for (int rr = 0; rr < 4; ++rr) {
        int row = row0 + m * 16 + g * 4 + rr;
        int col = colw + nt * 16 + c;
        float rg = 1.f / (1.f + __expf(-aR[m][nt][rr]));
        float zg = 1.f / (1.f + __expf(-aZ[m][nt][rr]));
        float t = aN[m][nt][rr] + rg * aHN[m][nt][rr];
        t = fminf(fmaxf(t, -15.f), 15.f);
        float ex = __expf(-2.f * t);
        float ng = (1.f - ex) / (1.f + ex);
        float ho = h[(size_t)row * HH + col];
        hout[(size_t)row * HH + col] = (1.f - zg) * ng + zg * ho;
      }
}

// ============ phase C: q_ue/q_ap in-kernel + edge-update MLP ============
__global__ __launch_bounds__(512, 2) void phaseC_kernel(
    const float* __restrict__ e, const float* __restrict__ hue_new,
    const float* __restrict__ hap_new,
    const float* __restrict__ ed_w1, const float* __restrict__ ed_b1,
    const float* __restrict__ ed_w2, const float* __restrict__ ed_b2,
    float* __restrict__ e_new) {
  __shared__ bf16_t ebuf[2][32 * 256];
  __shared__ bf16_t pbuf[32 * 256];
  __shared__ float qA[8 * 256];
  const int blk = blockIdx.x;              // 512 blocks
  const int b = blk >> 3, lc = blk & 7;
  const int tid = threadIdx.x, w = tid >> 6, lane = tid & 63;
  const int colw = w * 32, c = lane & 15, g = lane >> 4;
  const int l0 = lc * LGRP;

  f32x4 rs[4];
  ld_tile(e + (size_t)((b * LL + l0) * KK) * HH, tid, rs);

  // --- q_ue = hue_new[b]*Wed1[:, :H]^T + ed_b1 (register-direct) ---
  float qU[2][2][4];
  {
    f32x4 qacc[2][2];
#pragma unroll
    for (int nt = 0; nt < 2; ++nt) {
      float bv = ed_b1[colw + nt * 16 + c];
      f32x4 t = {bv, bv, bv, bv};
      qacc[0][nt] = t; qacc[1][nt] = t;
    }
#pragma unroll
    for (int ks = 0; ks < 8; ++ks) {
      const int ko = ks * 32 + g * 8;
      bf16x8 a0 = ld_a8(hue_new + (size_t)(b * KK + c) * HH + ko);
      bf16x8 a1 = ld_a8(hue_new + (size_t)(b * KK + 16 + c) * HH + ko);
#pragma unroll
      for (int nt = 0; nt < 2; ++nt) {
        bf16x8 bb = ld_a8(ed_w1 + (size_t)(colw + nt * 16 + c) * 768 + ko);
        qacc[0][nt] = __builtin_amdgcn_mfma_f32_16x16x32_bf16(a0, bb, qacc[0][nt], 0, 0, 0);
        qacc[1][nt] = __builtin_amdgcn_mfma_f32_16x16x32_bf16(a1, bb, qacc[1][nt], 0, 0, 0);
      }
    }
#pragma unroll
    for (int m = 0; m < 2; ++m)
#pragma unroll
      for (int nt = 0; nt < 2; ++nt)
#pragma unroll
        for (int rr = 0; rr < 4; ++rr) qU[m][nt][rr] = qacc[m][nt][rr];
  }

  // --- q_ap rows l0..l0+7 -> qA (no bias) ---
  {
    f32x4 sap[2];
    const f32x4 z4 = {0.f, 0.f, 0.f, 0.f};
    sap[0] = z4; sap[1] = z4;
    const float* Xap = hap_new + (size_t)(b * LL + l0) * HH;
#pragma unroll
    for (int ks = 0; ks < 8; ++ks) {
      const int ko = ks * 32 + g * 8;
      bf16x8 a = ld_a8(Xap + (size_t)(c & 7) * HH + ko);
#pragma unroll
      for (int nt = 0; nt < 2; ++nt) {
        bf16x8 bb = ld_a8(ed_w1 + (size_t)(colw + nt * 16 + c) * 768 + 256 + ko);
        sap[nt] = __builtin_amdgcn_mfma_f32_16x16x32_bf16(a, bb, sap[nt], 0, 0, 0);
      }
    }
    if (g < 2) {
#pragma unroll
      for (int nt = 0; nt < 2; ++nt)
#pragma unroll
        for (int rr = 0; rr < 4; ++rr)
          qA[(g * 4 + rr) * 256 + colw + nt * 16 + c] = sap[nt][rr];
    }
  }

  // --- register weights ---
  bf16x8 w1[2][8], w2[2][8];
#pragma unroll
  for (int nt = 0; nt < 2; ++nt)
#pragma unroll
    for (int ks = 0; ks < 8; ++ks) {
      w1[nt][ks] = ld_a8(ed_w1 + (size_t)(colw + nt * 16 + c) * 768 + 512 + ks * 32 + g * 8);
      w2[nt][ks] = ld_a8(ed_w2 + (size_t)(colw + nt * 16 + c) * 256 + ks * 32 + g * 8);
    }
  float b2v[2];
#pragma unroll
  for (int nt = 0; nt < 2; ++nt) b2v[nt] = ed_b2[colw + nt * 16 + c];

  wr_tile(ebuf[0], tid, rs);

  for (int li = 0; li < LGRP; ++li) {
    __syncthreads();                       // ebuf[li&1]+qA visible; prev pbuf readers done
    const int l = l0 + li;

    f32x4 a1[2][2];
#pragma unroll
    for (int nt = 0; nt < 2; ++nt) {
      float qa = qA[li * 256 + colw + nt * 16 + c];
#pragma unroll
      for (int rr = 0; rr < 4; ++rr) {
        a1[0][nt][rr] = qa + qU[0][nt][rr];
        a1[1][nt][rr] = qa + qU[1][nt][rr];
      }
    }
    const bf16_t* eb = ebuf[li & 1];
    const int swz = (c & 7) << 4;
#pragma unroll
    for (int ks = 0; ks < 8; ++ks) {
      const int kb = (ks * 32 + g * 8) * 2;
      bf16x8 a0 = *(const bf16x8*)((const char*)eb + c * 512 + (kb ^ swz));
      bf16x8 a1f = *(const bf16x8*)((const char*)eb + (16 + c) * 512 + (kb ^ swz));
#pragma unroll
      for (int nt = 0; nt < 2; ++nt) {
        a1[0][nt] = __builtin_amdgcn_mfma_f32_16x16x32_bf16(a0,  w1[nt][ks], a1[0][nt], 0, 0, 0);
        a1[1][nt] = __builtin_amdgcn_mfma_f32_16x16x32_bf16(a1f, w1[nt][ks], a1[1][nt], 0, 0, 0);
      }
    }
    if (li + 1 < LGRP) ld_tile(e + (size_t)((b * LL + l + 1) * KK) * HH, tid, rs);

    // relu -> pbuf
#pragma unroll
    for (int m = 0; m < 2; ++m)
#pragma unroll
      for (int nt = 0; nt < 2; ++nt)
#pragma unroll
        for (int rr = 0; rr < 4; ++rr) {
          int row = m * 16 + g * 4 + rr;
          int col = colw + nt * 16 + c;
          float v = fmaxf(a1[m][nt][rr], 0.f);
          int off = row * 512 + ((col * 2) ^ ((row & 7) << 4));
          *(bf16_t*)((char*)pbuf + off) = (__bf16)v;
        }
    __syncthreads();                       // pbuf visible

    f32x4 a2[2][2];
#pragma unroll
    for (int nt = 0; nt < 2; ++nt) {
      f32x4 t = {b2v[nt], b2v[nt], b2v[nt], b2v[nt]};
      a2[0][nt] = t; a2[1][nt] = t;
    }
#pragma unroll
    for (int ks = 0; ks < 8; ++ks) {
      const int kb = (ks * 32 + g * 8) * 2;
      bf16x8 a0 = *(const bf16x8*)((const char*)pbuf + c * 512 + (kb ^ swz));
      bf16x8 a1f = *(const bf16x8*)((const char*)pbuf + (16 + c) * 512 + (kb ^ swz));
#pragma unroll
      for (int nt = 0; nt < 2; ++nt) {
        a2[0][nt] = __builtin_amdgcn_mfma_f32_16x16x32_bf16(a0,  w2[nt][ks], a2[0][nt], 0, 0, 0);
        a2[1][nt] = __builtin_amdgcn_mfma_f32_16x16x32_bf16(a1f, w2[nt][ks], a2[1][nt], 0, 0, 0);
      }
    }
#pragma unroll
    for (int m = 0; m < 2; ++m)
#pragma unroll
      for (int nt = 0; nt < 2; ++nt)
#pragma unroll
        for (int rr = 0; rr < 4; ++rr) {
          int row = m * 16 + g * 4 + rr;
          int col = colw + nt * 16 + c;
          e_new[(size_t)((b * LL + l) * KK + row) * HH + colw + nt * 16 + c] = a2[m][nt][rr];
        }
    if (li + 1 < LGRP) wr_tile(ebuf[(li + 1) & 1], tid, rs);
  }
}

extern "C" void kernel_launch(void* const* d_in, const int* in_sizes, int n_in,
                              void* d_out, int out_size, void* d_ws, size_t ws_size,
                              hipStream_t stream) {
  const float* h_ue   = (const float*)d_in[0];
  const float* h_ap   = (const float*)d_in[1];
  const float* e      = (const float*)d_in[2];
  const float* a2u_w1 = (const float*)d_in[3];
  const float* a2u_b1 = (const float*)d_in[4];
  const float* a2u_w2 = (const float*)d_in[5];
  const float* a2u_b2 = (const float*)d_in[6];
  const float* u2a_w1 = (const float*)d_in[7];
  const float* u2a_b1 = (const float*)d_in[8];
  const float* u2a_w2 = (const float*)d_in[9];
  const float* u2a_b2 = (const float*)d_in[10];
  const float* ue_wih = (const float*)d_in[11];
  const float* ue_bih = (const float*)d_in[12];
  const float* ue_whh = (const float*)d_in[13];
  const float* ue_bhh = (const float*)d_in[14];
  const float* ap_wih = (const float*)d_in[15];
  const float* ap_bih = (const float*)d_in[16];
  const float* ap_whh = (const float*)d_in[17];
  const float* ap_bhh = (const float*)d_in[18];
  const float* ed_w1  = (const float*)d_in[19];
  const float* ed_b1  = (const float*)d_in[20];
  const float* ed_w2  = (const float*)d_in[21];
  const float* ed_b2  = (const float*)d_in[22];

  float* part = (float*)d_ws;           // 8 * 524288 f32
  float* R_ap = part + 4194304;         // 1048576 f32

  float* out      = (float*)d_out;
  float* hue_new  = out;                // 524288
  float* hap_new  = out + 524288;       // 1048576
  float* e_new    = out + 1572864;      // 33554432

  phaseA_kernel<<<512, 512, 0, stream>>>(e, h_ue, h_ap,
                                         a2u_w1, a2u_b1, u2a_w1, u2a_b1,
                                         part, R_ap);
  node_kernel<<<192, 256, 0, stream>>>(part, R_ap,
                                       a2u_w2, a2u_b2, u2a_w2, u2a_b2,
                                       h_ue, ue_wih, ue_bih, ue_whh, ue_bhh,
                                       h_ap, ap_wih, ap_bih, ap_whh, ap_bhh,
                                       hue_new, hap_new);
  phaseC_kernel<<<512, 512, 0, stream>>>(e, hue_new, hap_new,
                                         ed_w1, ed_b1, ed_w2, ed_b2, e_new);
}

// Round 7
// 253.146 us; speedup vs baseline: 1.3332x; 1.3140x over previous
//
#include <hip/hip_runtime.h>

#define HH 256   // H
#define BB 64    // B
#define KK 32    // K
#define LL 64    // L
#define LGRP 8   // l's per edge-kernel block

typedef __bf16 bf16_t;
typedef __attribute__((ext_vector_type(8))) __bf16 bf16x8;
typedef __attribute__((ext_vector_type(4))) float f32x4;

// ---- load 8 contiguous f32 -> bf16x8 ----
__device__ __forceinline__ bf16x8 ld_a8(const float* __restrict__ p) {
  const f32x4* q = (const f32x4*)p;
  f32x4 a = q[0], b = q[1];
  bf16x8 r;
  r[0] = (__bf16)a[0]; r[1] = (__bf16)a[1]; r[2] = (__bf16)a[2]; r[3] = (__bf16)a[3];
  r[4] = (__bf16)b[0]; r[5] = (__bf16)b[1]; r[6] = (__bf16)b[2]; r[7] = (__bf16)b[3];
  return r;
}
__device__ __forceinline__ bf16x8 ld_a8s(const float* __restrict__ p, float sc) {
  const f32x4* q = (const f32x4*)p;
  f32x4 a = q[0], b = q[1];
  bf16x8 r;
  r[0] = (__bf16)(a[0]*sc); r[1] = (__bf16)(a[1]*sc); r[2] = (__bf16)(a[2]*sc); r[3] = (__bf16)(a[3]*sc);
  r[4] = (__bf16)(b[0]*sc); r[5] = (__bf16)(b[1]*sc); r[6] = (__bf16)(b[2]*sc); r[7] = (__bf16)(b[3]*sc);
  return r;
}
// sum 8 partial slices (stride 524288 f32) -> bf16x8
__device__ __forceinline__ bf16x8 ld_sum8(const float* __restrict__ p) {
  f32x4 s0 = {0.f,0.f,0.f,0.f}, s1 = s0;
#pragma unroll
  for (int lc = 0; lc < 8; ++lc) {
    const f32x4* q = (const f32x4*)(p + (size_t)lc * 524288);
    s0 += q[0]; s1 += q[1];
  }
  bf16x8 r;
  r[0] = (__bf16)s0[0]; r[1] = (__bf16)s0[1]; r[2] = (__bf16)s0[2]; r[3] = (__bf16)s0[3];
  r[4] = (__bf16)s1[0]; r[5] = (__bf16)s1[1]; r[6] = (__bf16)s1[2]; r[7] = (__bf16)s1[3];
  return r;
}

// ---- e-tile staging (512 threads): 16 f32/thread -> regs -> swizzled bf16 LDS ----
__device__ __forceinline__ void ld_tile(const float* __restrict__ E, int tid, f32x4 r[4]) {
  const f32x4* q = (const f32x4*)(E + tid * 16);
  r[0] = q[0]; r[1] = q[1]; r[2] = q[2]; r[3] = q[3];
}
__device__ __forceinline__ void wr_tile(bf16_t* buf, int tid, const f32x4 r[4]) {
  int row = tid >> 4;
  int colb = (tid & 15) * 32;
  bf16x8 v0, v1;
  v0[0] = (__bf16)r[0][0]; v0[1] = (__bf16)r[0][1]; v0[2] = (__bf16)r[0][2]; v0[3] = (__bf16)r[0][3];
  v0[4] = (__bf16)r[1][0]; v0[5] = (__bf16)r[1][1]; v0[6] = (__bf16)r[1][2]; v0[7] = (__bf16)r[1][3];
  v1[0] = (__bf16)r[2][0]; v1[1] = (__bf16)r[2][1]; v1[2] = (__bf16)r[2][2]; v1[3] = (__bf16)r[2][3];
  v1[4] = (__bf16)r[3][0]; v1[5] = (__bf16)r[3][1]; v1[6] = (__bf16)r[3][2]; v1[7] = (__bf16)r[3][3];
  int swz = (row & 7) << 4;
  *(bf16x8*)((char*)buf + row * 512 + (colb ^ swz)) = v0;
  *(bf16x8*)((char*)buf + row * 512 + ((colb + 16) ^ swz)) = v1;
}

// acc[2][4] += A(32x256 f32 global)*B(bf16 row-major)^T  (4-wave, 64-col wave)
template<int LDB>
__device__ __forceinline__ void mm_f32A(const float* __restrict__ A,
                                        const bf16_t* __restrict__ B,
                                        f32x4 acc[2][4], int lane) {
  const int c = lane & 15, g = lane >> 4;
#pragma unroll
  for (int ks = 0; ks < 8; ++ks) {
    const int ko = ks * 32 + g * 8;
    bf16x8 a0 = ld_a8(A + (size_t)c * HH + ko);
    bf16x8 a1 = ld_a8(A + (size_t)(16 + c) * HH + ko);
#pragma unroll
    for (int nt = 0; nt < 4; ++nt) {
      bf16x8 bb = *(const bf16x8*)(B + (size_t)(nt * 16 + c) * LDB + ko);
      acc[0][nt] = __builtin_amdgcn_mfma_f32_16x16x32_bf16(a0, bb, acc[0][nt], 0, 0, 0);
      acc[1][nt] = __builtin_amdgcn_mfma_f32_16x16x32_bf16(a1, bb, acc[1][nt], 0, 0, 0);
    }
  }
}

// acc[2][4] += A(32x256 f32 global)*B(f32 global, cvt+scale)^T
template<int LDB>
__device__ __forceinline__ void mm_f32AB(const float* __restrict__ A,
                                         const float* __restrict__ B,
                                         f32x4 acc[2][4], int lane, float sc) {
  const int c = lane & 15, g = lane >> 4;
#pragma unroll
  for (int ks = 0; ks < 8; ++ks) {
    const int ko = ks * 32 + g * 8;
    bf16x8 a0 = ld_a8(A + (size_t)c * HH + ko);
    bf16x8 a1 = ld_a8(A + (size_t)(16 + c) * HH + ko);
#pragma unroll
    for (int nt = 0; nt < 4; ++nt) {
      bf16x8 bb = ld_a8s(B + (size_t)(nt * 16 + c) * LDB + ko, sc);
      acc[0][nt] = __builtin_amdgcn_mfma_f32_16x16x32_bf16(a0, bb, acc[0][nt], 0, 0, 0);
      acc[1][nt] = __builtin_amdgcn_mfma_f32_16x16x32_bf16(a1, bb, acc[1][nt], 0, 0, 0);
    }
  }
}

// acc[2][4] += (Σ_lc part)(32x256)*B(f32, cvt+scale)^T — reduce fused into A-fragments
__device__ __forceinline__ void mm_partA(const float* __restrict__ P,
                                         const float* __restrict__ B,
                                         f32x4 acc[2][4], int lane, float sc) {
  const int c = lane & 15, g = lane >> 4;
#pragma unroll
  for (int ks = 0; ks < 8; ++ks) {
    const int ko = ks * 32 + g * 8;
    bf16x8 a0 = ld_sum8(P + (size_t)c * HH + ko);
    bf16x8 a1 = ld_sum8(P + (size_t)(16 + c) * HH + ko);
#pragma unroll
    for (int nt = 0; nt < 4; ++nt) {
      bf16x8 bb = ld_a8s(B + (size_t)(nt * 16 + c) * HH + ko, sc);
      acc[0][nt] = __builtin_amdgcn_mfma_f32_16x16x32_bf16(a0, bb, acc[0][nt], 0, 0, 0);
      acc[1][nt] = __builtin_amdgcn_mfma_f32_16x16x32_bf16(a1, bb, acc[1][nt], 0, 0, 0);
    }
  }
}

// acc[2][4] += LDS(32x256 bf16 swizzled)*B(f32 global cvt)^T
__device__ __forceinline__ void mm_lds_f32B(const bf16_t* lds,
                                            const float* __restrict__ B,
                                            f32x4 acc[2][4], int lane) {
  const int c = lane & 15, g = lane >> 4;
  const int swz = (c & 7) << 4;
#pragma unroll
  for (int ks = 0; ks < 8; ++ks) {
    const int kb = (ks * 32 + g * 8) * 2;
    bf16x8 a0 = *(const bf16x8*)((const char*)lds + c * 512 + (kb ^ swz));
    bf16x8 a1 = *(const bf16x8*)((const char*)lds + (16 + c) * 512 + (kb ^ swz));
#pragma unroll
    for (int nt = 0; nt < 4; ++nt) {
      bf16x8 bb = ld_a8(B + (size_t)(nt * 16 + c) * HH + ks * 32 + g * 8);
      acc[0][nt] = __builtin_amdgcn_mfma_f32_16x16x32_bf16(a0, bb, acc[0][nt], 0, 0, 0);
      acc[1][nt] = __builtin_amdgcn_mfma_f32_16x16x32_bf16(a1, bb, acc[1][nt], 0, 0, 0);
    }
  }
}

// ---------------- prep: the 4 matrices consumed as bf16 by the edge kernels ----------------
// [0,131072) a2u_w1 ; [131072,262144) u2a_w1 ; [262144,458752) ed_w1 ; [458752,524288) ed_w2
__global__ __launch_bounds__(256) void prep_kernel(
    const float* w0, const float* w1, const float* w2, const float* w3, bf16_t* wb) {
  int i = blockIdx.x * 256 + threadIdx.x;
  const float* s; int o;
  if      (i < 131072) { s = w0; o = i; }
  else if (i < 262144) { s = w1; o = i - 131072; }
  else if (i < 458752) { s = w2; o = i - 262144; }
  else                 { s = w3; o = i - 458752; }
  wb[i] = (__bf16)s[o];
}

// ---------------- fused pair of projections: out = X*W^T + bias (bf16 W) ----------------
template<int LDW>
__global__ __launch_bounds__(256) void proj2_kernel(
    const float* __restrict__ X0, const bf16_t* __restrict__ W0,
    const float* __restrict__ b0, float* __restrict__ out0, int n0,
    const float* __restrict__ X1, const bf16_t* __restrict__ W1,
    const float* __restrict__ b1, float* __restrict__ out1) {
  const int blk = blockIdx.x;
  const float* X; const bf16_t* W; const float* bias; float* out; int row0;
  if (blk < n0) { X = X0; W = W0; bias = b0; out = out0; row0 = blk * 32; }
  else          { X = X1; W = W1; bias = b1; out = out1; row0 = (blk - n0) * 32; }
  const int tid = threadIdx.x, w = tid >> 6, lane = tid & 63;
  const int colw = w * 64, c = lane & 15, g = lane >> 4;
  f32x4 acc[2][4];
#pragma unroll
  for (int nt = 0; nt < 4; ++nt) {
    float bv = bias ? bias[colw + nt * 16 + c] : 0.f;
    f32x4 t = {bv, bv, bv, bv};
    acc[0][nt] = t; acc[1][nt] = t;
  }
  mm_f32A<LDW>(X + (size_t)row0 * HH, W + (size_t)colw * LDW, acc, lane);
#pragma unroll
  for (int m = 0; m < 2; ++m)
#pragma unroll
    for (int nt = 0; nt < 4; ++nt)
#pragma unroll
      for (int rr = 0; rr < 4; ++rr) {
        int row = row0 + m * 16 + g * 4 + rr;
        out[(size_t)row * HH + colw + nt * 16 + c] = acc[m][nt][rr];
      }
}

// ---------------- phase A (R4-proven): layer-1 of both MLPs, relu, reductions ----------------
// 512 threads = 8 waves; wave owns 32 output cols; bf16 weights register-resident.
// NOTE (R5/R6 lesson): do NOT fuse p_ue/p_ap MFMA prologues or inline f32 weight cvt here —
// that pushed VGPR demand past the allocator's comfort, it chose 128 and spilled (+60us).
__global__ __launch_bounds__(512) void phaseA_kernel(
    const float* __restrict__ e, const float* __restrict__ p_ap,
    const float* __restrict__ p_ue,
    const bf16_t* __restrict__ wu1e, const bf16_t* __restrict__ wa1e,
    float* __restrict__ part, float* __restrict__ R_ap) {
  __shared__ bf16_t ebuf[2][32 * 256];
  const int blk = blockIdx.x;              // 512 blocks
  const int b = blk >> 3, lc = blk & 7;
  const int tid = threadIdx.x, w = tid >> 6, lane = tid & 63;
  const int colw = w * 32, c = lane & 15, g = lane >> 4;
  const int l0 = lc * LGRP;

  // loop-invariant weight fragments (64+64 VGPRs)
  bf16x8 wU[2][8], wA[2][8];
#pragma unroll
  for (int nt = 0; nt < 2; ++nt)
#pragma unroll
    for (int ks = 0; ks < 8; ++ks) {
      size_t off = (size_t)(colw + nt * 16 + c) * 512 + ks * 32 + g * 8;
      wU[nt][ks] = *(const bf16x8*)(wu1e + off);
      wA[nt][ks] = *(const bf16x8*)(wa1e + off);
    }

  // p_ue init values (k-row dependent, b-const across loop)
  float pue[2][2][4];
#pragma unroll
  for (int m = 0; m < 2; ++m)
#pragma unroll
    for (int nt = 0; nt < 2; ++nt)
#pragma unroll
      for (int rr = 0; rr < 4; ++rr)
        pue[m][nt][rr] = p_ue[(size_t)(b * KK + m * 16 + g * 4 + rr) * HH + colw + nt * 16 + c];

  f32x4 accU[2][2];
  const f32x4 z4 = {0.f, 0.f, 0.f, 0.f};
#pragma unroll
  for (int m = 0; m < 2; ++m)
#pragma unroll
    for (int nt = 0; nt < 2; ++nt) accU[m][nt] = z4;

  f32x4 rs[4];
  ld_tile(e + (size_t)((b * LL + l0) * KK) * HH, tid, rs);
  wr_tile(ebuf[0], tid, rs);

  for (int li = 0; li < LGRP; ++li) {
    __syncthreads();                       // ebuf[li&1] visible; prev readers done
    const int l = l0 + li;
    if (li + 1 < LGRP) ld_tile(e + (size_t)((b * LL + l + 1) * KK) * HH, tid, rs);

    f32x4 aU[2][2], aA[2][2];
#pragma unroll
    for (int nt = 0; nt < 2; ++nt) {
      float pa = p_ap[(size_t)(b * LL + l) * HH + colw + nt * 16 + c];
      f32x4 t = {pa, pa, pa, pa};
      aA[0][nt] = t; aA[1][nt] = t;
#pragma unroll
      for (int rr = 0; rr < 4; ++rr) {
        aU[0][nt][rr] = pue[0][nt][rr];
        aU[1][nt][rr] = pue[1][nt][rr];
      }
    }
    const bf16_t* eb = ebuf[li & 1];
    const int swz = (c & 7) << 4;
#pragma unroll
    for (int ks = 0; ks < 8; ++ks) {
      const int kb = (ks * 32 + g * 8) * 2;
      bf16x8 a0 = *(const bf16x8*)((const char*)eb + c * 512 + (kb ^ swz));
      bf16x8 a1 = *(const bf16x8*)((const char*)eb + (16 + c) * 512 + (kb ^ swz));
#pragma unroll
      for (int nt = 0; nt < 2; ++nt) {
        aU[0][nt] = __builtin_amdgcn_mfma_f32_16x16x32_bf16(a0, wU[nt][ks], aU[0][nt], 0, 0, 0);
        aU[1][nt] = __builtin_amdgcn_mfma_f32_16x16x32_bf16(a1, wU[nt][ks], aU[1][nt], 0, 0, 0);
        aA[0][nt] = __builtin_amdgcn_mfma_f32_16x16x32_bf16(a0, wA[nt][ks], aA[0][nt], 0, 0, 0);
        aA[1][nt] = __builtin_amdgcn_mfma_f32_16x16x32_bf16(a1, wA[nt][ks], aA[1][nt], 0, 0, 0);
      }
    }
    __syncthreads();                       // ebuf[li&1] reads done
    if (li + 1 < LGRP) wr_tile(ebuf[(li + 1) & 1], tid, rs);

    // u2a: relu + k-reduce -> R_ap[b,l,:]  (no bias; /K folded at node m-GEMM)
#pragma unroll
    for (int nt = 0; nt < 2; ++nt) {
      float s = 0.f;
#pragma unroll
      for (int m = 0; m < 2; ++m)
#pragma unroll
        for (int rr = 0; rr < 4; ++rr) s += fmaxf(aU[m][nt][rr], 0.f);
      s += __shfl_xor(s, 16);
      s += __shfl_xor(s, 32);
      if (lane < 16)
        R_ap[(size_t)(b * LL + l) * HH + colw + nt * 16 + lane] = s;
    }
    // a2u: relu accumulate over l
#pragma unroll
    for (int m = 0; m < 2; ++m)
#pragma unroll
      for (int nt = 0; nt < 2; ++nt)
#pragma unroll
        for (int rr = 0; rr < 4; ++rr)
          accU[m][nt][rr] += fmaxf(aA[m][nt][rr], 0.f);
  }

#pragma unroll
  for (int m = 0; m < 2; ++m)
#pragma unroll
    for (int nt = 0; nt < 2; ++nt)
#pragma unroll
      for (int rr = 0; rr < 4; ++rr) {
        int krow = m * 16 + g * 4 + rr;
        part[(size_t)((lc * BB + b) * KK + krow) * HH + colw + nt * 16 + c] = accU[m][nt][rr];
      }
}

// ============ node: reduce + layer-2 msg GEMM + GRU (both node types) ============
__global__ __launch_bounds__(256) void node_kernel(
    const float* __restrict__ part, const float* __restrict__ R_ap,
    const float* __restrict__ a2u_w2, const float* __restrict__ a2u_b2,
    const float* __restrict__ u2a_w2, const float* __restrict__ u2a_b2,
    const float* __restrict__ h_ue, const float* __restrict__ ue_wih,
    const float* __restrict__ ue_bih, const float* __restrict__ ue_whh,
    const float* __restrict__ ue_bhh,
    const float* __restrict__ h_ap, const float* __restrict__ ap_wih,
    const float* __restrict__ ap_bih, const float* __restrict__ ap_whh,
    const float* __restrict__ ap_bhh,
    float* __restrict__ hue_new, float* __restrict__ hap_new) {
  __shared__ bf16_t mbuf[32 * 256];
  const int blk = blockIdx.x;              // 192 blocks: 64 UE + 128 AP
  const bool ue = blk < 64;
  const int row0 = ue ? blk * 32 : (blk - 64) * 32;
  const int tid = threadIdx.x, w = tid >> 6, lane = tid & 63;
  const int colw = w * 64, c = lane & 15, g = lane >> 4;
  const float* W2  = ue ? a2u_w2 : u2a_w2;
  const float* b2  = ue ? a2u_b2 : u2a_b2;
  const float* h   = ue ? h_ue : h_ap;
  const float* wih = ue ? ue_wih : ap_wih;
  const float* whh = ue ? ue_whh : ap_whh;
  const float* bih = ue ? ue_bih : ap_bih;
  const float* bhh = ue ? ue_bhh : ap_bhh;
  float* hout      = ue ? hue_new : hap_new;
  const float sc   = ue ? (1.f / 64.f) : (1.f / 32.f);   // /L or /K

  // --- m = R*(W2*sc)^T + b2 ---
  f32x4 acc[2][4];
#pragma unroll
  for (int nt = 0; nt < 4; ++nt) {
    float bv = b2[colw + nt * 16 + c];
    f32x4 t = {bv, bv, bv, bv};
    acc[0][nt] = t; acc[1][nt] = t;
  }
  if (ue) mm_partA(part + (size_t)row0 * HH, W2 + (size_t)colw * HH, acc, lane, sc);
  else    mm_f32AB<HH>(R_ap + (size_t)row0 * HH, W2 + (size_t)colw * HH, acc, lane, sc);

  // m -> swizzled bf16 LDS (no relu)
#pragma unroll
  for (int m = 0; m < 2; ++m)
#pragma unroll
    for (int nt = 0; nt < 4; ++nt)
#pragma unroll
      for (int rr = 0; rr < 4; ++rr) {
        int row = m * 16 + g * 4 + rr;
        int col = colw + nt * 16 + c;
        int off = row * 512 + ((col * 2) ^ ((row & 7) << 4));
        *(bf16_t*)((char*)mbuf + off) = (__bf16)acc[m][nt][rr];
      }
  __syncthreads();

  // --- GRU ---
  f32x4 aR[2][4], aZ[2][4], aN[2][4], aHN[2][4];
#pragma unroll
  for (int nt = 0; nt < 4; ++nt) {
    int col = colw + nt * 16 + c;
    float vR = bih[col] + bhh[col];
    float vZ = bih[256 + col] + bhh[256 + col];
    float vN = bih[512 + col];
    float vH = bhh[512 + col];
    f32x4 tR = {vR, vR, vR, vR}, tZ = {vZ, vZ, vZ, vZ};
    f32x4 tN = {vN, vN, vN, vN}, tH = {vH, vH, vH, vH};
    aR[0][nt] = tR; aR[1][nt] = tR;
    aZ[0][nt] = tZ; aZ[1][nt] = tZ;
    aN[0][nt] = tN; aN[1][nt] = tN;
    aHN[0][nt] = tH; aHN[1][nt] = tH;
  }
  const float* Hp = h + (size_t)row0 * HH;
  mm_lds_f32B(mbuf, wih + (size_t)(0   + colw) * HH, aR, lane);
  mm_f32AB<HH>(Hp,  whh + (size_t)(0   + colw) * HH, aR, lane, 1.f);
  mm_lds_f32B(mbuf, wih + (size_t)(256 + colw) * HH, aZ, lane);
  mm_f32AB<HH>(Hp,  whh + (size_t)(256 + colw) * HH, aZ, lane, 1.f);
  mm_lds_f32B(mbuf, wih + (size_t)(512 + colw) * HH, aN, lane);
  mm_f32AB<HH>(Hp,  whh + (size_t)(512 + colw) * HH, aHN, lane, 1.f);
#pragma unroll
  for (int m = 0; m < 2; ++m)
#pragma unroll
    for (int nt = 0; nt < 4; ++nt)
#pragma unroll
      for (int rr = 0; rr < 4; ++rr) {
        int row = row0 + m * 16 + g * 4 + rr;
        int col = colw + nt * 16 + c;
        float rg = 1.f / (1.f + __expf(-aR[m][nt][rr]));
        float zg = 1.f / (1.f + __expf(-aZ[m][nt][rr]));
        float t = aN[m][nt][rr] + rg * aHN[m][nt][rr];
        t = fminf(fmaxf(t, -15.f), 15.f);
        float ex = __expf(-2.f * t);
        float ng = (1.f - ex) / (1.f + ex);
        float ho = h[(size_t)row * HH + col];
        hout[(size_t)row * HH + col] = (1.f - zg) * ng + zg * ho;
      }
}

// ---------------- phase C (R4-proven): edge update, weights in regs ----------------
__global__ __launch_bounds__(512) void phaseC_kernel(
    const float* __restrict__ e, const float* __restrict__ q_ue,
    const float* __restrict__ q_ap,
    const bf16_t* __restrict__ wed1e, const bf16_t* __restrict__ wed2,
    const float* __restrict__ ed_b2, float* __restrict__ e_new) {
  __shared__ bf16_t ebuf[2][32 * 256];
  __shared__ bf16_t pbuf[32 * 256];
  const int blk = blockIdx.x;              // 512 blocks
  const int b = blk >> 3, lc = blk & 7;
  const int tid = threadIdx.x, w = tid >> 6, lane = tid & 63;
  const int colw = w * 32, c = lane & 15, g = lane >> 4;
  const int l0 = lc * LGRP;

  bf16x8 w1[2][8], w2[2][8];
#pragma unroll
  for (int nt = 0; nt < 2; ++nt)
#pragma unroll
    for (int ks = 0; ks < 8; ++ks) {
      w1[nt][ks] = *(const bf16x8*)(wed1e + (size_t)(colw + nt * 16 + c) * 768 + ks * 32 + g * 8);
      w2[nt][ks] = *(const bf16x8*)(wed2  + (size_t)(colw + nt * 16 + c) * 256 + ks * 32 + g * 8);
    }

  float qU[2][2][4];
#pragma unroll
  for (int m = 0; m < 2; ++m)
#pragma unroll
    for (int nt = 0; nt < 2; ++nt)
#pragma unroll
      for (int rr = 0; rr < 4; ++rr)
        qU[m][nt][rr] = q_ue[(size_t)(b * KK + m * 16 + g * 4 + rr) * HH + colw + nt * 16 + c];
  float b2v[2];
#pragma unroll
  for (int nt = 0; nt < 2; ++nt) b2v[nt] = ed_b2[colw + nt * 16 + c];

  f32x4 rs[4];
  ld_tile(e + (size_t)((b * LL + l0) * KK) * HH, tid, rs);
  wr_tile(ebuf[0], tid, rs);

  for (int li = 0; li < LGRP; ++li) {
    __syncthreads();                       // ebuf[li&1] visible; prev pbuf readers done
    const int l = l0 + li;

    f32x4 a1[2][2];
#pragma unroll
    for (int nt = 0; nt < 2; ++nt) {
      float qa = q_ap[(size_t)(b * LL + l) * HH + colw + nt * 16 + c];
#pragma unroll
      for (int rr = 0; rr < 4; ++rr) {
        a1[0][nt][rr] = qa + qU[0][nt][rr];
        a1[1][nt][rr] = qa + qU[1][nt][rr];
      }
    }
    const bf16_t* eb = ebuf[li & 1];
    const int swz = (c & 7) << 4;
#pragma unroll
    for (int ks = 0; ks < 8; ++ks) {
      const int kb = (ks * 32 + g * 8) * 2;
      bf16x8 a0 = *(const bf16x8*)((const char*)eb + c * 512 + (kb ^ swz));
      bf16x8 a1f = *(const bf16x8*)((const char*)eb + (16 + c) * 512 + (kb ^ swz));
#pragma unroll
      for (int nt = 0; nt < 2; ++nt) {
        a1[0][nt] = __builtin_amdgcn_mfma_f32_16x16x32_bf16(a0,  w1[nt][ks], a1[0][nt], 0, 0, 0);
        a1[1][nt] = __builtin_amdgcn_mfma_f32_16x16x32_bf16(a1f, w1[nt][ks], a1[1][nt], 0, 0, 0);
      }
    }
    if (li + 1 < LGRP) ld_tile(e + (size_t)((b * LL + l + 1) * KK) * HH, tid, rs);

    // relu -> pbuf (this wave's 32-col slice)
#pragma unroll
    for (int m = 0; m < 2; ++m)
#pragma unroll
      for (int nt = 0; nt < 2; ++nt)
#pragma unroll
        for (int rr = 0; rr < 4; ++rr) {
          int row = m * 16 + g * 4 + rr;
          int col = colw + nt * 16 + c;
          float v = fmaxf(a1[m][nt][rr], 0.f);
          int off = row * 512 + ((col * 2) ^ ((row & 7) << 4));
          *(bf16_t*)((char*)pbuf + off) = (__bf16)v;
        }
    __syncthreads();                       // pbuf visible (ebuf reads already done)

    f32x4 a2[2][2];
#pragma unroll
    for (int nt = 0; nt < 2; ++nt) {
      f32x4 t = {b2v[nt], b2v[nt], b2v[nt], b2v[nt]};
      a2[0][nt] = t; a2[1][nt] = t;
    }
#pragma unroll
    for (int ks = 0; ks < 8; ++ks) {
      const int kb = (ks * 32 + g * 8) * 2;
      bf16x8 a0 = *(const bf16x8*)((const char*)pbuf + c * 512 + (kb ^ swz));
      bf16x8 a1f = *(const bf16x8*)((const char*)pbuf + (16 + c) * 512 + (kb ^ swz));
#pragma unroll
      for (int nt = 0; nt < 2; ++nt) {
        a2[0][nt] = __builtin_amdgcn_mfma_f32_16x16x32_bf16(a0,  w2[nt][ks], a2[0][nt], 0, 0, 0);
        a2[1][nt] = __builtin_amdgcn_mfma_f32_16x16x32_bf16(a1f, w2[nt][ks], a2[1][nt], 0, 0, 0);
      }
    }
#pragma unroll
    for (int m = 0; m < 2; ++m)
#pragma unroll
      for (int nt = 0; nt < 2; ++nt)
#pragma unroll
        for (int rr = 0; rr < 4; ++rr) {
          int row = m * 16 + g * 4 + rr;
          e_new[(size_t)((b * LL + l) * KK + row) * HH + colw + nt * 16 + c] = a2[m][nt][rr];
        }
    if (li + 1 < LGRP) wr_tile(ebuf[(li + 1) & 1], tid, rs);
  }
}

extern "C" void kernel_launch(void* const* d_in, const int* in_sizes, int n_in,
                              void* d_out, int out_size, void* d_ws, size_t ws_size,
                              hipStream_t stream) {
  const float* h_ue   = (const float*)d_in[0];
  const float* h_ap   = (const float*)d_in[1];
  const float* e      = (const float*)d_in[2];
  const float* a2u_w1 = (const float*)d_in[3];
  const float* a2u_b1 = (const float*)d_in[4];
  const float* a2u_w2 = (const float*)d_in[5];
  const float* a2u_b2 = (const float*)d_in[6];
  const float* u2a_w1 = (const float*)d_in[7];
  const float* u2a_b1 = (const float*)d_in[8];
  const float* u2a_w2 = (const float*)d_in[9];
  const float* u2a_b2 = (const float*)d_in[10];
  const float* ue_wih = (const float*)d_in[11];
  const float* ue_bih = (const float*)d_in[12];
  const float* ue_whh = (const float*)d_in[13];
  const float* ue_bhh = (const float*)d_in[14];
  const float* ap_wih = (const float*)d_in[15];
  const float* ap_bih = (const float*)d_in[16];
  const float* ap_whh = (const float*)d_in[17];
  const float* ap_bhh = (const float*)d_in[18];
  const float* ed_w1  = (const float*)d_in[19];
  const float* ed_b1  = (const float*)d_in[20];
  const float* ed_w2  = (const float*)d_in[21];
  const float* ed_b2  = (const float*)d_in[22];

  // workspace: bf16 weights then f32 scratch
  bf16_t* wb   = (bf16_t*)d_ws;
  bf16_t* wa1  = wb;                    // a2u_w1 (256x512)
  bf16_t* wu1  = wb + 131072;           // u2a_w1 (256x512)
  bf16_t* wed1 = wb + 262144;           // ed_w1  (256x768)
  bf16_t* wed2 = wb + 458752;           // ed_w2  (256x256)
  float* fbase = (float*)((char*)d_ws + 1048576);
  float* p_ap = fbase;                  // 1048576
  float* p_ue = p_ap + 1048576;         // 524288
  float* q_ue = p_ue + 524288;          // 524288
  float* q_ap = q_ue + 524288;          // 1048576
  float* part = q_ap + 1048576;         // 4194304
  float* R_ap = part + 4194304;         // 1048576

  float* out      = (float*)d_out;
  float* hue_new  = out;                // 524288
  float* hap_new  = out + 524288;       // 1048576
  float* e_new    = out + 1572864;      // 33554432

  prep_kernel<<<2048, 256, 0, stream>>>(a2u_w1, u2a_w1, ed_w1, ed_w2, wb);
  // p_ap = h_ap*Wa1_h^T + b1 ; p_ue = h_ue*Wu1_h^T + b1
  proj2_kernel<512><<<192, 256, 0, stream>>>(h_ap, wa1, a2u_b1, p_ap, 128,
                                             h_ue, wu1, u2a_b1, p_ue);
  phaseA_kernel<<<512, 512, 0, stream>>>(e, p_ap, p_ue, wu1 + 256, wa1 + 256,
                                         part, R_ap);
  node_kernel<<<192, 256, 0, stream>>>(part, R_ap,
                                       a2u_w2, a2u_b2, u2a_w2, u2a_b2,
                                       h_ue, ue_wih, ue_bih, ue_whh, ue_bhh,
                                       h_ap, ap_wih, ap_bih, ap_whh, ap_bhh,
                                       hue_new, hap_new);
  // q_ue = hue_new*Wed1[:, :H]^T + ed_b1 ; q_ap = hap_new*Wed1[:, H:2H]^T
  proj2_kernel<768><<<192, 256, 0, stream>>>(hue_new, wed1, ed_b1, q_ue, 64,
                                             hap_new, wed1 + 256, nullptr, q_ap);
  phaseC_kernel<<<512, 512, 0, stream>>>(e, q_ue, q_ap, wed1 + 512, wed2, ed_b2, e_new);
}